// Round 1
// baseline (262.570 us; speedup 1.0000x reference)
//
#include <hip/hip_runtime.h>

typedef __bf16 bf16;
typedef __attribute__((ext_vector_type(8))) __bf16 bf16x8;
typedef __attribute__((ext_vector_type(4))) __bf16 bf16x4;
typedef __attribute__((ext_vector_type(4))) float floatx4;

#define MFMA16(a, b, c) __builtin_amdgcn_mfma_f32_16x16x32_bf16((a), (b), (c), 0, 0, 0)

// ---------------------------------------------------------------------------
// Kernel 0: W [1024][64] fp32 -> wT [3][64][1024] bf16 (transposed, bf16)
// ---------------------------------------------------------------------------
__global__ void prep_w(const float* __restrict__ Wq, const float* __restrict__ Wk,
                       const float* __restrict__ Wv, bf16* __restrict__ wT) {
    int tid = blockIdx.x * 256 + threadIdx.x;   // [0, 3*64*1024)
    int mat = tid >> 16;
    int r = tid & 65535;                        // h*1024 + c
    int h = r >> 10, c = r & 1023;
    const float* W = (mat == 0) ? Wq : (mat == 1) ? Wk : Wv;
    wT[tid] = (bf16)W[c * 64 + h];
}

// ---------------------------------------------------------------------------
// Kernel 1: QKV projection via MFMA, computed transposed: D[m=h'][n=t]
//   A[m][k] = wT[m][c],  B[k][n] = x[t][c]  (both contiguous along k) -> no LDS
// Outputs: q,k as bf16 [b*2048+t][64]; v as vT bf16 [b*64+h][2048]
// ---------------------------------------------------------------------------
__global__ __launch_bounds__(256) void proj_qkv(const float* __restrict__ x,
                                                const bf16* __restrict__ wT,
                                                bf16* __restrict__ q,
                                                bf16* __restrict__ k,
                                                bf16* __restrict__ vT) {
    const int lane = threadIdx.x & 63;
    const int w = threadIdx.x >> 6;     // wave 0..3
    const int l15 = lane & 15;
    const int quad = lane >> 4;
    const int R0 = blockIdx.x * 32;     // t-tile of 32

    floatx4 acc[3][2] = {};

    const float* xp0 = x + (size_t)(R0 + l15) * 1024 + quad * 8;
    const float* xp1 = x + (size_t)(R0 + 16 + l15) * 1024 + quad * 8;
    const bf16* ap0 = wT + (size_t)((w * 3 + 0) * 16 + l15) * 1024 + quad * 8;
    const bf16* ap1 = wT + (size_t)((w * 3 + 1) * 16 + l15) * 1024 + quad * 8;
    const bf16* ap2 = wT + (size_t)((w * 3 + 2) * 16 + l15) * 1024 + quad * 8;

    #pragma unroll 2
    for (int c0 = 0; c0 < 1024; c0 += 32) {
        floatx4 f00 = *(const floatx4*)(xp0 + c0);
        floatx4 f01 = *(const floatx4*)(xp0 + c0 + 4);
        floatx4 f10 = *(const floatx4*)(xp1 + c0);
        floatx4 f11 = *(const floatx4*)(xp1 + c0 + 4);
        bf16x8 a0 = *(const bf16x8*)(ap0 + c0);
        bf16x8 a1 = *(const bf16x8*)(ap1 + c0);
        bf16x8 a2 = *(const bf16x8*)(ap2 + c0);

        bf16x8 b0, b1;
        b0[0] = (bf16)f00[0]; b0[1] = (bf16)f00[1]; b0[2] = (bf16)f00[2]; b0[3] = (bf16)f00[3];
        b0[4] = (bf16)f01[0]; b0[5] = (bf16)f01[1]; b0[6] = (bf16)f01[2]; b0[7] = (bf16)f01[3];
        b1[0] = (bf16)f10[0]; b1[1] = (bf16)f10[1]; b1[2] = (bf16)f10[2]; b1[3] = (bf16)f10[3];
        b1[4] = (bf16)f11[0]; b1[5] = (bf16)f11[1]; b1[6] = (bf16)f11[2]; b1[7] = (bf16)f11[3];

        acc[0][0] = MFMA16(a0, b0, acc[0][0]);
        acc[0][1] = MFMA16(a0, b1, acc[0][1]);
        acc[1][0] = MFMA16(a1, b0, acc[1][0]);
        acc[1][1] = MFMA16(a1, b1, acc[1][1]);
        acc[2][0] = MFMA16(a2, b0, acc[2][0]);
        acc[2][1] = MFMA16(a2, b1, acc[2][1]);
    }

    // Epilogue. C-layout: value (i,nt,r) is at out-row m = (w*3+i)*16 + quad*4 + r
    // (i.e. mat = m/64, h = m%64), out-col t = R0 + nt*16 + l15.
    #pragma unroll
    for (int i = 0; i < 3; i++) {
        int mtile = w * 3 + i;
        int mat = mtile >> 2;                          // uniform per (w,i)
        int hbase = ((mtile & 3) << 4) + (quad << 2);  // h of r=0
        #pragma unroll
        for (int nt = 0; nt < 2; nt++) {
            int t = R0 + nt * 16 + l15;
            bf16x4 pk;
            pk[0] = (bf16)acc[i][nt][0];
            pk[1] = (bf16)acc[i][nt][1];
            pk[2] = (bf16)acc[i][nt][2];
            pk[3] = (bf16)acc[i][nt][3];
            if (mat == 0) {
                *(bf16x4*)(q + (size_t)t * 64 + hbase) = pk;   // 4 consecutive h
            } else if (mat == 1) {
                *(bf16x4*)(k + (size_t)t * 64 + hbase) = pk;
            } else {
                int b = t >> 11, tt = t & 2047;
                #pragma unroll
                for (int r = 0; r < 4; r++)
                    vT[(size_t)(b * 64 + hbase + r) * 2048 + tt] = pk[r];
            }
        }
    }
}

// ---------------------------------------------------------------------------
// Kernel 2: causal flash attention. BM=32 (2 waves, 16 rows each), BN=64.
// Grid = 8 batches * 64 mt-tiles = 512 blocks, mt swizzled for balance.
// ---------------------------------------------------------------------------
#define KP 72   // padded LDS row stride in bf16 elems (144 B: 16B-aligned, 2-way banks only)

__global__ __launch_bounds__(128) void flash(const bf16* __restrict__ q,
                                             const bf16* __restrict__ k,
                                             const bf16* __restrict__ vT,
                                             float* __restrict__ out) {
    __shared__ bf16 kt[64 * KP];
    __shared__ bf16 vt[64 * KP];
    __shared__ bf16 ps[32 * KP];

    const int b = blockIdx.x >> 6;
    const int p = blockIdx.x & 63;
    const int mt = (p & 1) ? (63 - (p >> 1)) : (p >> 1);   // pair light+heavy

    const int tid = threadIdx.x;        // 0..127
    const int w = tid >> 6;             // wave 0/1 -> rows w*16..+16
    const int lane = tid & 63;
    const int l15 = lane & 15;
    const int quad = lane >> 4;

    // Q fragments (A-layout): m = mt*32 + w*16 + l15, k = h = hc*32 + quad*8 + j
    const int m = mt * 32 + w * 16 + l15;
    const bf16* qp = q + (size_t)(b * 2048 + m) * 64 + quad * 8;
    bf16x8 qf0 = *(const bf16x8*)qp;
    bf16x8 qf1 = *(const bf16x8*)(qp + 32);

    floatx4 o[4] = {};
    float mi[4], li[4];
    #pragma unroll
    for (int r = 0; r < 4; r++) { mi[r] = -1e30f; li[r] = 0.f; }

    const int rowg0 = mt * 32 + w * 16 + quad * 4;   // + r
    const int jmax = (mt * 32 + 31) >> 6;

    for (int jt = 0; jt <= jmax; jt++) {
        __syncthreads();   // all waves done with previous kt/vt
        // stage K tile [kv=0..63][h=0..63] (contiguous 8KB in k)
        {
            const bf16* src = k + (size_t)(b * 2048 + jt * 64) * 64;
            #pragma unroll
            for (int s = 0; s < 4; s++) {
                int slot = tid + s * 128;                 // 0..511
                int row = slot >> 3, off = (slot & 7) * 8;
                *(bf16x8*)(kt + row * KP + off) = *(const bf16x8*)(src + row * 64 + off);
            }
            const bf16* vsrc = vT + (size_t)(b * 64) * 2048 + jt * 64;
            #pragma unroll
            for (int s = 0; s < 4; s++) {
                int slot = tid + s * 128;
                int row = slot >> 3, off = (slot & 7) * 8;   // row=h, off along t
                *(bf16x8*)(vt + row * KP + off) = *(const bf16x8*)(vsrc + (size_t)row * 2048 + off);
            }
        }
        __syncthreads();

        // S = Q K^T : B[k=h][n=kv] = kt[kv][h], contiguous along h
        floatx4 s[4] = {};
        #pragma unroll
        for (int nt = 0; nt < 4; nt++) {
            const bf16* kp0 = kt + (nt * 16 + l15) * KP + quad * 8;
            bf16x8 kb0 = *(const bf16x8*)kp0;
            bf16x8 kb1 = *(const bf16x8*)(kp0 + 32);
            s[nt] = MFMA16(qf0, kb0, s[nt]);
            s[nt] = MFMA16(qf1, kb1, s[nt]);
        }

        // scale + causal mask (only final tile can straddle the diagonal)
        const bool diag = (jt == jmax);
        #pragma unroll
        for (int nt = 0; nt < 4; nt++) {
            #pragma unroll
            for (int r = 0; r < 4; r++) {
                float val = s[nt][r] * 0.125f;
                if (diag) {
                    int kv = jt * 64 + nt * 16 + l15;
                    if (kv > rowg0 + r) val = -1e30f;
                }
                s[nt][r] = val;
            }
        }

        // online softmax, per row r (row's 64 cols live across the 16 lanes of this quad)
        float alpha[4];
        #pragma unroll
        for (int r = 0; r < 4; r++) {
            float mx = fmaxf(fmaxf(s[0][r], s[1][r]), fmaxf(s[2][r], s[3][r]));
            #pragma unroll
            for (int off = 1; off < 16; off <<= 1) mx = fmaxf(mx, __shfl_xor(mx, off, 64));
            float mnew = fmaxf(mi[r], mx);
            float a = __expf(mi[r] - mnew);
            mi[r] = mnew;
            float rs = 0.f;
            #pragma unroll
            for (int nt = 0; nt < 4; nt++) {
                float pv = __expf(s[nt][r] - mnew);
                s[nt][r] = pv;
                rs += pv;
            }
            #pragma unroll
            for (int off = 1; off < 16; off <<= 1) rs += __shfl_xor(rs, off, 64);
            li[r] = li[r] * a + rs;
            alpha[r] = a;
        }
        #pragma unroll
        for (int nt = 0; nt < 4; nt++)
            #pragma unroll
            for (int r = 0; r < 4; r++)
                o[nt][r] *= alpha[r];

        // P: C-layout -> LDS -> A-layout (wave-private rows; in-order LDS per wave)
        #pragma unroll
        for (int nt = 0; nt < 4; nt++) {
            #pragma unroll
            for (int r = 0; r < 4; r++)
                ps[(w * 16 + quad * 4 + r) * KP + nt * 16 + l15] = (bf16)s[nt][r];
        }

        // O += P V : A = ps[m][kv], B[k=kv][n=h] = vt[h][kv], contiguous along kv
        #pragma unroll
        for (int kc = 0; kc < 2; kc++) {
            bf16x8 af = *(const bf16x8*)(ps + (w * 16 + l15) * KP + kc * 32 + quad * 8);
            #pragma unroll
            for (int nt = 0; nt < 4; nt++) {
                bf16x8 vb = *(const bf16x8*)(vt + (nt * 16 + l15) * KP + kc * 32 + quad * 8);
                o[nt] = MFMA16(af, vb, o[nt]);
            }
        }
    }

    // epilogue: out fp32 [b][t][h]
    #pragma unroll
    for (int r = 0; r < 4; r++) {
        float inv = 1.f / li[r];
        int t = rowg0 + r;
        #pragma unroll
        for (int nt = 0; nt < 4; nt++)
            out[(size_t)(b * 2048 + t) * 64 + nt * 16 + l15] = o[nt][r] * inv;
    }
}

// ---------------------------------------------------------------------------
extern "C" void kernel_launch(void* const* d_in, const int* in_sizes, int n_in,
                              void* d_out, int out_size, void* d_ws, size_t ws_size,
                              hipStream_t stream) {
    const float* x  = (const float*)d_in[0];
    const float* Wq = (const float*)d_in[1];
    const float* Wk = (const float*)d_in[2];
    const float* Wv = (const float*)d_in[3];
    float* out = (float*)d_out;

    char* ws = (char*)d_ws;
    bf16* wT = (bf16*)ws;                               // 3*64*1024*2   = 393216 B
    bf16* q  = (bf16*)(ws + 393216);                    // 16384*64*2    = 2 MB
    bf16* k  = (bf16*)(ws + 393216 + 2097152);
    bf16* vT = (bf16*)(ws + 393216 + 2 * 2097152);      // [b*64+h][2048]

    hipLaunchKernelGGL(prep_w,   dim3(768), dim3(256), 0, stream, Wq, Wk, Wv, wT);
    hipLaunchKernelGGL(proj_qkv, dim3(512), dim3(256), 0, stream, x, wT, q, k, vT);
    hipLaunchKernelGGL(flash,    dim3(512), dim3(128), 0, stream, q, k, vT, out);
}

// Round 2
// 222.539 us; speedup vs baseline: 1.1799x; 1.1799x over previous
//
#include <hip/hip_runtime.h>

typedef __bf16 bf16;
typedef __attribute__((ext_vector_type(8))) __bf16 bf16x8;
typedef __attribute__((ext_vector_type(4))) __bf16 bf16x4;
typedef __attribute__((ext_vector_type(4))) float floatx4;

#define MFMA16(a, b, c) __builtin_amdgcn_mfma_f32_16x16x32_bf16((a), (b), (c), 0, 0, 0)

// ---------------------------------------------------------------------------
// Kernel 0: W [1024][64] fp32 -> wT [3][64][1024] bf16 (transposed, bf16)
// ---------------------------------------------------------------------------
__global__ void prep_w(const float* __restrict__ Wq, const float* __restrict__ Wk,
                       const float* __restrict__ Wv, bf16* __restrict__ wT) {
    int tid = blockIdx.x * 256 + threadIdx.x;   // [0, 3*64*1024)
    int mat = tid >> 16;
    int r = tid & 65535;                        // h*1024 + c
    int h = r >> 10, c = r & 1023;
    const float* W = (mat == 0) ? Wq : (mat == 1) ? Wk : Wv;
    wT[tid] = (bf16)W[c * 64 + h];
}

// ---------------------------------------------------------------------------
// Kernel 1: QKV projection via MFMA, computed transposed: D[m=h'][n=t].
// Block = 256 thr (4 waves) = ONE 16-row t-tile; wave w does m-tiles 3w..3w+2.
// Grid = 1024 blocks -> 4 blocks/CU, 4 waves/SIMD.
// q gets the 1/8 attention scale folded in.
// ---------------------------------------------------------------------------
__global__ __launch_bounds__(256) void proj_qkv(const float* __restrict__ x,
                                                const bf16* __restrict__ wT,
                                                bf16* __restrict__ q,
                                                bf16* __restrict__ k,
                                                bf16* __restrict__ vT) {
    const int lane = threadIdx.x & 63;
    const int w = threadIdx.x >> 6;     // wave 0..3
    const int l15 = lane & 15;
    const int quad = lane >> 4;
    const int T0 = blockIdx.x * 16;     // t-tile of 16

    floatx4 acc[3] = {};

    const float* xp = x + (size_t)(T0 + l15) * 1024 + quad * 8;
    const bf16* ap0 = wT + (size_t)((w * 3 + 0) * 16 + l15) * 1024 + quad * 8;
    const bf16* ap1 = wT + (size_t)((w * 3 + 1) * 16 + l15) * 1024 + quad * 8;
    const bf16* ap2 = wT + (size_t)((w * 3 + 2) * 16 + l15) * 1024 + quad * 8;

    #pragma unroll 4
    for (int c0 = 0; c0 < 1024; c0 += 32) {
        floatx4 f0 = *(const floatx4*)(xp + c0);
        floatx4 f1 = *(const floatx4*)(xp + c0 + 4);
        bf16x8 a0 = *(const bf16x8*)(ap0 + c0);
        bf16x8 a1 = *(const bf16x8*)(ap1 + c0);
        bf16x8 a2 = *(const bf16x8*)(ap2 + c0);

        bf16x8 bb;
        bb[0] = (bf16)f0[0]; bb[1] = (bf16)f0[1]; bb[2] = (bf16)f0[2]; bb[3] = (bf16)f0[3];
        bb[4] = (bf16)f1[0]; bb[5] = (bf16)f1[1]; bb[6] = (bf16)f1[2]; bb[7] = (bf16)f1[3];

        acc[0] = MFMA16(a0, bb, acc[0]);
        acc[1] = MFMA16(a1, bb, acc[1]);
        acc[2] = MFMA16(a2, bb, acc[2]);
    }

    // Epilogue. C-layout: (i,r) -> out-row m = (w*3+i)*16 + quad*4 + r
    // (mat = m/64, h = m%64), out-col t = T0 + l15.
    const int t = T0 + l15;
    #pragma unroll
    for (int i = 0; i < 3; i++) {
        int mtile = w * 3 + i;
        int mat = mtile >> 2;                          // wave-uniform
        int hbase = ((mtile & 3) << 4) + (quad << 2);  // h of r=0
        float sc = (mat == 0) ? 0.125f : 1.0f;         // fold 1/sqrt(64) into q
        bf16x4 pk;
        pk[0] = (bf16)(acc[i][0] * sc);
        pk[1] = (bf16)(acc[i][1] * sc);
        pk[2] = (bf16)(acc[i][2] * sc);
        pk[3] = (bf16)(acc[i][3] * sc);
        if (mat == 0) {
            *(bf16x4*)(q + (size_t)t * 64 + hbase) = pk;   // 4 consecutive h
        } else if (mat == 1) {
            *(bf16x4*)(k + (size_t)t * 64 + hbase) = pk;
        } else {
            int b = t >> 11, tt = t & 2047;
            #pragma unroll
            for (int r = 0; r < 4; r++)
                vT[(size_t)(b * 64 + hbase + r) * 2048 + tt] = pk[r];
        }
    }
}

// ---------------------------------------------------------------------------
// Kernel 2: causal flash attention, KV-split across waves.
// Block = 256 thr (4 waves) owns ONE 16-row Q tile; wave w processes a
// contiguous quarter of the causal KV tile range with private online-softmax
// state; K/V fragments load DIRECTLY from global (L2-resident, B-layouts by
// construction); no __syncthreads in the main loop. In-block merge at end.
// Grid = 8 * 128 = 1024 blocks * 4 waves = 4096 waves = 4 waves/SIMD.
// ---------------------------------------------------------------------------
#define KP 72   // ps row stride (bf16)

__global__ __launch_bounds__(256) void flash(const bf16* __restrict__ q,
                                             const bf16* __restrict__ k,
                                             const bf16* __restrict__ vT,
                                             float* __restrict__ out) {
    __shared__ bf16 ps[4][16 * KP];       // per-wave P round-trip
    __shared__ float Ms[4][16], Ls[4][16];
    __shared__ float Os[4][16][68];       // unnormalized partial O

    const int b = blockIdx.x >> 7;
    const int p = blockIdx.x & 127;
    const int mtg = (p & 1) ? (127 - (p >> 1)) : (p >> 1);  // pair light+heavy
    const int t0 = mtg * 16;

    const int tid = threadIdx.x;
    const int w = tid >> 6;
    const int lane = tid & 63;
    const int l15 = lane & 15;
    const int quad = lane >> 4;

    const int jd = mtg >> 2;        // the (only) diagonal-straddling KV tile
    const int ntt = jd + 1;         // total KV tiles for this Q tile
    const int js = (ntt * w) >> 2;
    const int je = (ntt * (w + 1)) >> 2;

    // Q fragments (A-layout): m = t0 + l15, k = h = quad*8 + j (+32)
    const bf16* qp = q + (size_t)(b * 2048 + t0 + l15) * 64 + quad * 8;
    bf16x8 qf0 = *(const bf16x8*)qp;
    bf16x8 qf1 = *(const bf16x8*)(qp + 32);

    floatx4 o[4] = {};
    float mi[4], li[4];
    #pragma unroll
    for (int r = 0; r < 4; r++) { mi[r] = -1e30f; li[r] = 0.f; }

    const int rowq = t0 + quad * 4;   // + r = this lane's output rows

    // hoisted per-n-tile base pointers
    const bf16* kb[4];
    const bf16* vb[4];
    #pragma unroll
    for (int nt = 0; nt < 4; nt++) {
        kb[nt] = k + (size_t)(b * 2048 + nt * 16 + l15) * 64 + quad * 8;
        vb[nt] = vT + (size_t)(b * 64 + nt * 16 + l15) * 2048 + quad * 8;
    }
    bf16* psw = ps[w];

    for (int jt = js; jt < je; jt++) {
        // S = Q K^T : B[k=h][n=kv] direct from k[t][h]
        floatx4 s[4] = {};
        #pragma unroll
        for (int nt = 0; nt < 4; nt++) {
            const bf16* kp = kb[nt] + (size_t)jt * 64 * 64;
            bf16x8 k0 = *(const bf16x8*)kp;
            bf16x8 k1 = *(const bf16x8*)(kp + 32);
            s[nt] = MFMA16(qf0, k0, s[nt]);
            s[nt] = MFMA16(qf1, k1, s[nt]);
        }

        // causal mask (only the diagonal tile straddles)
        if (jt == jd) {
            #pragma unroll
            for (int nt = 0; nt < 4; nt++) {
                int kv = jt * 64 + nt * 16 + l15;
                #pragma unroll
                for (int r = 0; r < 4; r++)
                    if (kv > rowq + r) s[nt][r] = -1e30f;
            }
        }

        // online softmax per row r (row's 64 cols across the 16 lanes of quad)
        float alpha[4];
        #pragma unroll
        for (int r = 0; r < 4; r++) {
            float mx = fmaxf(fmaxf(s[0][r], s[1][r]), fmaxf(s[2][r], s[3][r]));
            #pragma unroll
            for (int off = 1; off < 16; off <<= 1) mx = fmaxf(mx, __shfl_xor(mx, off, 64));
            float mnew = fmaxf(mi[r], mx);
            float a = __expf(mi[r] - mnew);
            mi[r] = mnew;
            float rs = 0.f;
            #pragma unroll
            for (int nt = 0; nt < 4; nt++) {
                float pv = __expf(s[nt][r] - mnew);
                s[nt][r] = pv;
                rs += pv;
            }
            #pragma unroll
            for (int off = 1; off < 16; off <<= 1) rs += __shfl_xor(rs, off, 64);
            li[r] = li[r] * a + rs;
            alpha[r] = a;
        }
        #pragma unroll
        for (int nt = 0; nt < 4; nt++)
            #pragma unroll
            for (int r = 0; r < 4; r++)
                o[nt][r] *= alpha[r];

        // P: C-layout -> LDS -> A-layout (wave-private, no barrier needed)
        #pragma unroll
        for (int nt = 0; nt < 4; nt++)
            #pragma unroll
            for (int r = 0; r < 4; r++)
                psw[(quad * 4 + r) * KP + nt * 16 + l15] = (bf16)s[nt][r];

        // O += P V : B[k=kv][n=h] direct from vT[h][t]
        #pragma unroll
        for (int kc = 0; kc < 2; kc++) {
            bf16x8 af = *(const bf16x8*)(psw + l15 * KP + kc * 32 + quad * 8);
            #pragma unroll
            for (int nt = 0; nt < 4; nt++) {
                bf16x8 vv = *(const bf16x8*)(vb[nt] + jt * 64 + kc * 32);
                o[nt] = MFMA16(af, vv, o[nt]);
            }
        }
    }

    // dump partials to LDS
    #pragma unroll
    for (int r = 0; r < 4; r++) {
        if (l15 == 0) { Ms[w][quad * 4 + r] = mi[r]; Ls[w][quad * 4 + r] = li[r]; }
        #pragma unroll
        for (int nt = 0; nt < 4; nt++)
            Os[w][quad * 4 + r][nt * 16 + l15] = o[nt][r];
    }
    __syncthreads();

    // merge 4 partials: thread -> (row = tid>>4, 4 cols = (tid&15)*4)
    {
        int row = tid >> 4;
        int c4 = (tid & 15) * 4;
        float m0 = Ms[0][row], m1 = Ms[1][row], m2 = Ms[2][row], m3 = Ms[3][row];
        float Mg = fmaxf(fmaxf(m0, m1), fmaxf(m2, m3));
        float s0 = __expf(m0 - Mg), s1 = __expf(m1 - Mg);
        float s2 = __expf(m2 - Mg), s3 = __expf(m3 - Mg);
        float Lg = s0 * Ls[0][row] + s1 * Ls[1][row] + s2 * Ls[2][row] + s3 * Ls[3][row];
        float inv = 1.0f / Lg;
        float* op = out + (size_t)(b * 2048 + t0 + row) * 64 + c4;
        #pragma unroll
        for (int c = 0; c < 4; c++) {
            float v = s0 * Os[0][row][c4 + c] + s1 * Os[1][row][c4 + c] +
                      s2 * Os[2][row][c4 + c] + s3 * Os[3][row][c4 + c];
            op[c] = v * inv;
        }
    }
}

// ---------------------------------------------------------------------------
extern "C" void kernel_launch(void* const* d_in, const int* in_sizes, int n_in,
                              void* d_out, int out_size, void* d_ws, size_t ws_size,
                              hipStream_t stream) {
    const float* x  = (const float*)d_in[0];
    const float* Wq = (const float*)d_in[1];
    const float* Wk = (const float*)d_in[2];
    const float* Wv = (const float*)d_in[3];
    float* out = (float*)d_out;

    char* ws = (char*)d_ws;
    bf16* wT = (bf16*)ws;                               // 393216 B
    bf16* q  = (bf16*)(ws + 393216);                    // 2 MB
    bf16* k  = (bf16*)(ws + 393216 + 2097152);
    bf16* vT = (bf16*)(ws + 393216 + 2 * 2097152);      // [b*64+h][2048]

    hipLaunchKernelGGL(prep_w,   dim3(768),  dim3(256), 0, stream, Wq, Wk, Wv, wT);
    hipLaunchKernelGGL(proj_qkv, dim3(1024), dim3(256), 0, stream, x, wT, q, k, vT);
    hipLaunchKernelGGL(flash,    dim3(1024), dim3(256), 0, stream, q, k, vT, out);
}

// Round 3
// 221.712 us; speedup vs baseline: 1.1843x; 1.0037x over previous
//
#include <hip/hip_runtime.h>

typedef __bf16 bf16;
typedef __attribute__((ext_vector_type(8))) __bf16 bf16x8;
typedef __attribute__((ext_vector_type(4))) __bf16 bf16x4;
typedef __attribute__((ext_vector_type(4))) float floatx4;

#define MFMA16(a, b, c) __builtin_amdgcn_mfma_f32_16x16x32_bf16((a), (b), (c), 0, 0, 0)

__device__ __forceinline__ void gl2lds16(const float* g, float* l) {
    __builtin_amdgcn_global_load_lds(
        (const __attribute__((address_space(1))) unsigned int*)g,
        (__attribute__((address_space(3))) unsigned int*)l, 16, 0, 0);
}

// ---------------------------------------------------------------------------
// Kernel 0: W [1024][64] fp32 -> wT [3][64][1024] bf16 (transposed, bf16)
// ---------------------------------------------------------------------------
__global__ void prep_w(const float* __restrict__ Wq, const float* __restrict__ Wk,
                       const float* __restrict__ Wv, bf16* __restrict__ wT) {
    int tid = blockIdx.x * 256 + threadIdx.x;   // [0, 3*64*1024)
    int mat = tid >> 16;
    int r = tid & 65535;                        // h*1024 + c
    int h = r >> 10, c = r & 1023;
    const float* W = (mat == 0) ? Wq : (mat == 1) ? Wk : Wv;
    wT[tid] = (bf16)W[c * 64 + h];
}

// ---------------------------------------------------------------------------
// Kernel 1: QKV projection. Block = 256 thr = ONE 16-row t-tile.
// Phase 1: async-DMA the 64 KB x tile into LDS (global_load_lds width=16,
//          ~4096 granules in flight -> HBM latency fully covered).
//          LDS layout: granule slot (row, gs) holds global granule gs^(row&7)
//          (swizzle applied on the GLOBAL side since LDS dest must be linear)
//          -> compute-side ds_read_b128 is bank-conflict-free.
// Phase 2: wave w computes m-tiles 3w..3w+2 (A = wT from L2), B from LDS.
// 64 KB LDS -> 2 blocks/CU; block B stages while block A computes.
// ---------------------------------------------------------------------------
__global__ __launch_bounds__(256) void proj_qkv(const float* __restrict__ x,
                                                const bf16* __restrict__ wT,
                                                bf16* __restrict__ q,
                                                bf16* __restrict__ k,
                                                bf16* __restrict__ vT) {
    __shared__ float xs[16 * 1024];     // 64 KB, swizzled granules

    const int tid = threadIdx.x;
    const int lane = tid & 63;
    const int w = tid >> 6;
    const int l15 = lane & 15;
    const int quad = lane >> 4;
    const int T0 = blockIdx.x * 16;

    // ---- Phase 1: async stage. call c: row=c, slot gs = w*64+lane,
    //      global granule g = gs ^ (c&7)  (permutes within 128B -> coalesced)
    {
        const float* xt = x + (size_t)T0 * 1024;
        #pragma unroll
        for (int c = 0; c < 16; c++) {
            int gs = w * 64 + lane;
            int g = gs ^ (c & 7);
            gl2lds16(xt + (size_t)c * 1024 + g * 4, xs + (c * 256 + gs) * 4);
        }
    }
    __syncthreads();   // drains vmcnt (compiler emits full waitcnt before barrier)

    // ---- Phase 2: compute
    floatx4 acc[3] = {};
    const bf16* ap0 = wT + (size_t)((w * 3 + 0) * 16 + l15) * 1024 + quad * 8;
    const bf16* ap1 = wT + (size_t)((w * 3 + 1) * 16 + l15) * 1024 + quad * 8;
    const bf16* ap2 = wT + (size_t)((w * 3 + 2) * 16 + l15) * 1024 + quad * 8;
    const float* xrow = xs + l15 * 1024;
    const int swz = l15 & 7;

    #pragma unroll 4
    for (int c0 = 0; c0 < 1024; c0 += 32) {
        int g0 = (c0 >> 2) + quad * 2;                       // low 3 bits = quad*2
        floatx4 f0 = *(const floatx4*)(xrow + (((g0 + 0) ^ swz) << 2));
        floatx4 f1 = *(const floatx4*)(xrow + (((g0 + 1) ^ swz) << 2));
        bf16x8 a0 = *(const bf16x8*)(ap0 + c0);
        bf16x8 a1 = *(const bf16x8*)(ap1 + c0);
        bf16x8 a2 = *(const bf16x8*)(ap2 + c0);

        bf16x8 bb;
        bb[0] = (bf16)f0[0]; bb[1] = (bf16)f0[1]; bb[2] = (bf16)f0[2]; bb[3] = (bf16)f0[3];
        bb[4] = (bf16)f1[0]; bb[5] = (bf16)f1[1]; bb[6] = (bf16)f1[2]; bb[7] = (bf16)f1[3];

        acc[0] = MFMA16(a0, bb, acc[0]);
        acc[1] = MFMA16(a1, bb, acc[1]);
        acc[2] = MFMA16(a2, bb, acc[2]);
    }

    // Epilogue. C-layout: (i,r) -> out-row m = (w*3+i)*16 + quad*4 + r
    // (mat = m/64, h = m%64), out-col t = T0 + l15.  q gets 1/8 scale folded.
    const int t = T0 + l15;
    #pragma unroll
    for (int i = 0; i < 3; i++) {
        int mtile = w * 3 + i;
        int mat = mtile >> 2;                          // wave-uniform
        int hbase = ((mtile & 3) << 4) + (quad << 2);
        float sc = (mat == 0) ? 0.125f : 1.0f;
        bf16x4 pk;
        pk[0] = (bf16)(acc[i][0] * sc);
        pk[1] = (bf16)(acc[i][1] * sc);
        pk[2] = (bf16)(acc[i][2] * sc);
        pk[3] = (bf16)(acc[i][3] * sc);
        if (mat == 0) {
            *(bf16x4*)(q + (size_t)t * 64 + hbase) = pk;
        } else if (mat == 1) {
            *(bf16x4*)(k + (size_t)t * 64 + hbase) = pk;
        } else {
            int b = t >> 11, tt = t & 2047;
            #pragma unroll
            for (int r = 0; r < 4; r++)
                vT[(size_t)(b * 64 + hbase + r) * 2048 + tt] = pk[r];
        }
    }
}

// ---------------------------------------------------------------------------
// Kernel 2: causal flash attention, 8-way KV split.
// Block = 512 thr (8 waves) owns ONE 16-row Q tile; wave w takes a contiguous
// eighth of the causal KV tiles with private online-softmax state; K/V frags
// load directly from global (L2-resident). LDS ps (loop) unions with Os
// (merge) -> 35.8 KB -> 4 blocks/CU * 8 waves = 8 waves/SIMD, grid co-resident.
// __launch_bounds__(512,8) caps VGPR at 64 for full occupancy.
// ---------------------------------------------------------------------------
#define KP 72

__global__ __launch_bounds__(512, 8) void flash(const bf16* __restrict__ q,
                                                const bf16* __restrict__ k,
                                                const bf16* __restrict__ vT,
                                                float* __restrict__ out) {
    __shared__ char smem[8 * 16 * 68 * 4];   // union: ps (loop) / Os (merge)
    __shared__ float Ms[8][16], Ls[8][16];
    bf16* psall = (bf16*)smem;
    float* OsB = (float*)smem;

    const int b = blockIdx.x >> 7;
    const int p = blockIdx.x & 127;
    const int mtg = (p & 1) ? (127 - (p >> 1)) : (p >> 1);  // pair light+heavy
    const int t0 = mtg * 16;

    const int tid = threadIdx.x;
    const int w = tid >> 6;          // wave 0..7
    const int lane = tid & 63;
    const int l15 = lane & 15;
    const int quad = lane >> 4;

    const int jd = mtg >> 2;         // diagonal-straddling KV tile
    const int ntt = jd + 1;
    const int js = (ntt * w) >> 3;
    const int je = (ntt * (w + 1)) >> 3;

    // Q fragments (A-layout): m = t0 + l15, k = h = quad*8 + j (+32)
    const bf16* qp = q + (size_t)(b * 2048 + t0 + l15) * 64 + quad * 8;
    bf16x8 qf0 = *(const bf16x8*)qp;
    bf16x8 qf1 = *(const bf16x8*)(qp + 32);

    floatx4 o[4] = {};
    float mi[4], li[4];
    #pragma unroll
    for (int r = 0; r < 4; r++) { mi[r] = -1e30f; li[r] = 0.f; }

    const int rowq = t0 + quad * 4;

    // single bases; per-nt offsets are compile-time constants
    const bf16* kb0 = k + (size_t)(b * 2048 + l15) * 64 + quad * 8;    // + jt*4096 + nt*1024
    const bf16* vb0 = vT + (size_t)(b * 64 + l15) * 2048 + quad * 8;   // + nt*32768 + jt*64 + kc*32
    bf16* psw = psall + w * 16 * KP;

    for (int jt = js; jt < je; jt++) {
        // S = Q K^T : B[k=h][n=kv] direct from k[t][h]
        const bf16* kp = kb0 + (size_t)jt * 4096;
        floatx4 s[4] = {};
        #pragma unroll
        for (int nt = 0; nt < 4; nt++) {
            bf16x8 k0 = *(const bf16x8*)(kp + nt * 1024);
            bf16x8 k1 = *(const bf16x8*)(kp + nt * 1024 + 32);
            s[nt] = MFMA16(qf0, k0, s[nt]);
            s[nt] = MFMA16(qf1, k1, s[nt]);
        }

        // causal mask (only the diagonal tile straddles)
        if (jt == jd) {
            #pragma unroll
            for (int nt = 0; nt < 4; nt++) {
                int kv = jt * 64 + nt * 16 + l15;
                #pragma unroll
                for (int r = 0; r < 4; r++)
                    if (kv > rowq + r) s[nt][r] = -1e30f;
            }
        }

        // online softmax per row r (row's 64 cols across the quad's 16 lanes)
        float alpha[4];
        #pragma unroll
        for (int r = 0; r < 4; r++) {
            float mx = fmaxf(fmaxf(s[0][r], s[1][r]), fmaxf(s[2][r], s[3][r]));
            #pragma unroll
            for (int off = 1; off < 16; off <<= 1) mx = fmaxf(mx, __shfl_xor(mx, off, 64));
            float mnew = fmaxf(mi[r], mx);
            float a = __expf(mi[r] - mnew);
            mi[r] = mnew;
            float rs = 0.f;
            #pragma unroll
            for (int nt = 0; nt < 4; nt++) {
                float pv = __expf(s[nt][r] - mnew);
                s[nt][r] = pv;
                rs += pv;
            }
            #pragma unroll
            for (int off = 1; off < 16; off <<= 1) rs += __shfl_xor(rs, off, 64);
            li[r] = li[r] * a + rs;
            alpha[r] = a;
        }
        #pragma unroll
        for (int nt = 0; nt < 4; nt++)
            #pragma unroll
            for (int r = 0; r < 4; r++)
                o[nt][r] *= alpha[r];

        // P: C-layout -> LDS -> A-layout (wave-private, no barrier)
        #pragma unroll
        for (int nt = 0; nt < 4; nt++)
            #pragma unroll
            for (int r = 0; r < 4; r++)
                psw[(quad * 4 + r) * KP + nt * 16 + l15] = (bf16)s[nt][r];

        // O += P V : B[k=kv][n=h] direct from vT[h][t]
        const bf16* vp = vb0 + jt * 64;
        #pragma unroll
        for (int kc = 0; kc < 2; kc++) {
            bf16x8 af = *(const bf16x8*)(psw + l15 * KP + kc * 32 + quad * 8);
            #pragma unroll
            for (int nt = 0; nt < 4; nt++) {
                bf16x8 vv = *(const bf16x8*)(vp + nt * 32768 + kc * 32);
                o[nt] = MFMA16(af, vv, o[nt]);
            }
        }
    }

    __syncthreads();   // everyone done with ps before Os overwrites it

    // dump partials (Os region unions with ps)
    #pragma unroll
    for (int r = 0; r < 4; r++) {
        if (l15 == 0) { Ms[w][quad * 4 + r] = mi[r]; Ls[w][quad * 4 + r] = li[r]; }
        #pragma unroll
        for (int nt = 0; nt < 4; nt++)
            OsB[(w * 16 + quad * 4 + r) * 68 + nt * 16 + l15] = o[nt][r];
    }
    __syncthreads();

    // merge 8 partials: thread -> (row = tid>>5, 2 cols = (tid&31)*2)
    {
        int row = tid >> 5;
        int c2 = (tid & 31) * 2;
        float Mg = -1e30f;
        #pragma unroll
        for (int u = 0; u < 8; u++) Mg = fmaxf(Mg, Ms[u][row]);
        float Lg = 0.f, v0 = 0.f, v1 = 0.f;
        #pragma unroll
        for (int u = 0; u < 8; u++) {
            float sw = __expf(Ms[u][row] - Mg);
            Lg += sw * Ls[u][row];
            const float* Or = OsB + (u * 16 + row) * 68 + c2;
            v0 += sw * Or[0];
            v1 += sw * Or[1];
        }
        float inv = 1.0f / Lg;
        float* op = out + (size_t)(b * 2048 + t0 + row) * 64 + c2;
        op[0] = v0 * inv;
        op[1] = v1 * inv;
    }
}

// ---------------------------------------------------------------------------
extern "C" void kernel_launch(void* const* d_in, const int* in_sizes, int n_in,
                              void* d_out, int out_size, void* d_ws, size_t ws_size,
                              hipStream_t stream) {
    const float* x  = (const float*)d_in[0];
    const float* Wq = (const float*)d_in[1];
    const float* Wk = (const float*)d_in[2];
    const float* Wv = (const float*)d_in[3];
    float* out = (float*)d_out;

    char* ws = (char*)d_ws;
    bf16* wT = (bf16*)ws;                               // 393216 B
    bf16* q  = (bf16*)(ws + 393216);                    // 2 MB
    bf16* k  = (bf16*)(ws + 393216 + 2097152);
    bf16* vT = (bf16*)(ws + 393216 + 2 * 2097152);      // [b*64+h][2048]

    hipLaunchKernelGGL(prep_w,   dim3(768),  dim3(256), 0, stream, Wq, Wk, Wv, wT);
    hipLaunchKernelGGL(proj_qkv, dim3(1024), dim3(256), 0, stream, x, wT, q, k, vT);
    hipLaunchKernelGGL(flash,    dim3(1024), dim3(512), 0, stream, q, k, vT, out);
}

// Round 4
// 157.850 us; speedup vs baseline: 1.6634x; 1.4046x over previous
//
#include <hip/hip_runtime.h>

typedef __bf16 bf16;
typedef __attribute__((ext_vector_type(8))) __bf16 bf16x8;
typedef __attribute__((ext_vector_type(4))) __bf16 bf16x4;
typedef __attribute__((ext_vector_type(4))) float floatx4;

#define MFMA16(a, b, c) __builtin_amdgcn_mfma_f32_16x16x32_bf16((a), (b), (c), 0, 0, 0)

// ---------------------------------------------------------------------------
// Kernel 0: W [1024][64] fp32 x3 -> wTf, FRAGMENT-MAJOR bf16:
//   wTf[(((mt*32 + kc)*4 + q)*16 + l)*8 + j] = A[m = mt*16+l][k = kc*32+q*8+j]
//   where A[m][c] = W_{m/64}[c][m%64].  One bf16x8 A-frag load per (mt,kc)
//   is then 16 B/lane, lane-consecutive (coalesced, streaming in kc).
// ---------------------------------------------------------------------------
__global__ void prep_w(const float* __restrict__ Wq, const float* __restrict__ Wk,
                       const float* __restrict__ Wv, bf16* __restrict__ wTf) {
    int tid = blockIdx.x * 256 + threadIdx.x;   // [0, 196608)
    int j = tid & 7;
    int l = (tid >> 3) & 15;
    int q = (tid >> 7) & 3;
    int kc = (tid >> 9) & 31;
    int mt = tid >> 14;                          // 0..11
    int mat = mt >> 2;
    int h = ((mt & 3) << 4) + l;
    int c = kc * 32 + q * 8 + j;
    const float* W = (mat == 0) ? Wq : (mat == 1) ? Wk : Wv;
    wTf[tid] = (bf16)W[c * 64 + h];
}

// ---------------------------------------------------------------------------
// Kernel 1: QKV projection. Block = 512 thr (8 waves) = ONE 32-row t-tile.
// Stage: vectorized copy x(fp32, global) -> xs(bf16, LDS, stride 1032) —
//   independent iterations so loads pipeline; converts once per element.
// Compute: wave w -> m-tiles 3*(w>>1)..+2, t-half (w&1). A-frags stream from
//   frag-major wTf (L2) with explicit next-iter register prefetch; B-frags
//   are single ds_read_b128 per iter. 66 KB LDS -> 2 blocks/CU; grid 512 =
//   exactly 2/CU so one block stages while the other computes.
// ---------------------------------------------------------------------------
#define XSTR 1032   // bf16 row stride: 2064 B (16B-aligned; uniform bank phases)

__global__ __launch_bounds__(512, 4) void proj_qkv(const float* __restrict__ x,
                                                   const bf16* __restrict__ wTf,
                                                   bf16* __restrict__ q,
                                                   bf16* __restrict__ k,
                                                   bf16* __restrict__ vT) {
    __shared__ bf16 xs[32 * XSTR];   // 66 KB

    const int tid = threadIdx.x;
    const int lane = tid & 63;
    const int w = tid >> 6;
    const int l15 = lane & 15;
    const int quad = lane >> 4;
    const int T0 = blockIdx.x * 32;

    // ---- stage: thread (r = tid>>4, cm = tid&15) copies row r, cols cm*8 + c*128
    {
        const int r = tid >> 4;
        const int cm = tid & 15;
        const float* gsrc = x + (size_t)(T0 + r) * 1024 + cm * 8;
        bf16* ldst = xs + r * XSTR + cm * 8;
        #pragma unroll
        for (int c = 0; c < 8; c++) {
            floatx4 u = *(const floatx4*)(gsrc + c * 128);
            floatx4 v = *(const floatx4*)(gsrc + c * 128 + 4);
            bf16x8 pk;
            pk[0] = (bf16)u[0]; pk[1] = (bf16)u[1]; pk[2] = (bf16)u[2]; pk[3] = (bf16)u[3];
            pk[4] = (bf16)v[0]; pk[5] = (bf16)v[1]; pk[6] = (bf16)v[2]; pk[7] = (bf16)v[3];
            *(bf16x8*)(ldst + c * 128) = pk;
        }
    }
    __syncthreads();

    // ---- compute
    const int mtg = w >> 1;            // 0..3 -> m-tiles 3*mtg..3*mtg+2
    const int tloc = (w & 1) * 16;     // t-half within the 32-row tile

    floatx4 acc[3] = {};
    const bf16* aw0 = wTf + (size_t)(mtg * 3 + 0) * 16384 + lane * 8;
    const bf16* aw1 = wTf + (size_t)(mtg * 3 + 1) * 16384 + lane * 8;
    const bf16* aw2 = wTf + (size_t)(mtg * 3 + 2) * 16384 + lane * 8;
    const bf16* xr = xs + (tloc + l15) * XSTR + quad * 8;

    bf16x8 a0 = *(const bf16x8*)aw0;
    bf16x8 a1 = *(const bf16x8*)aw1;
    bf16x8 a2 = *(const bf16x8*)aw2;

    #pragma unroll 4
    for (int kc = 0; kc < 32; kc++) {
        // prefetch next A-frags (kc=31 reads 1KB slack past wTf - never used)
        bf16x8 n0 = *(const bf16x8*)(aw0 + kc * 512 + 512);
        bf16x8 n1 = *(const bf16x8*)(aw1 + kc * 512 + 512);
        bf16x8 n2 = *(const bf16x8*)(aw2 + kc * 512 + 512);
        bf16x8 bb = *(const bf16x8*)(xr + kc * 32);
        acc[0] = MFMA16(a0, bb, acc[0]);
        acc[1] = MFMA16(a1, bb, acc[1]);
        acc[2] = MFMA16(a2, bb, acc[2]);
        a0 = n0; a1 = n1; a2 = n2;
    }

    // Epilogue. C-layout: (i,r) -> out-row m = (mtg*3+i)*16 + quad*4 + r
    // (mat = m/64, h = m%64), out-col t = T0 + tloc + l15. q gets 1/8 folded.
    const int t = T0 + tloc + l15;
    #pragma unroll
    for (int i = 0; i < 3; i++) {
        int mtile = mtg * 3 + i;
        int mat = mtile >> 2;                          // wave-uniform
        int hbase = ((mtile & 3) << 4) + (quad << 2);
        float sc = (mat == 0) ? 0.125f : 1.0f;
        bf16x4 pk;
        pk[0] = (bf16)(acc[i][0] * sc);
        pk[1] = (bf16)(acc[i][1] * sc);
        pk[2] = (bf16)(acc[i][2] * sc);
        pk[3] = (bf16)(acc[i][3] * sc);
        if (mat == 0) {
            *(bf16x4*)(q + (size_t)t * 64 + hbase) = pk;
        } else if (mat == 1) {
            *(bf16x4*)(k + (size_t)t * 64 + hbase) = pk;
        } else {
            int b = t >> 11, tt = t & 2047;
            #pragma unroll
            for (int r = 0; r < 4; r++)
                vT[(size_t)(b * 64 + hbase + r) * 2048 + tt] = pk[r];
        }
    }
}

// ---------------------------------------------------------------------------
// Kernel 2: causal flash attention, 8-way KV split across waves.
// __launch_bounds__(512,4): 128-VGPR cap -> NO spills (R3's (512,8) forced
// scratch traffic: 63MB fetch / 50MB write). XCD batch affinity: b=blockIdx&7
// so each XCD's K+V working set is one batch (512 KB, L2-resident).
// ---------------------------------------------------------------------------
#define KP 72

__global__ __launch_bounds__(512, 4) void flash(const bf16* __restrict__ q,
                                                const bf16* __restrict__ k,
                                                const bf16* __restrict__ vT,
                                                float* __restrict__ out) {
    __shared__ char smem[8 * 16 * 68 * 4];   // union: ps (loop) / Os (merge)
    __shared__ float Ms[8][16], Ls[8][16];
    bf16* psall = (bf16*)smem;
    float* OsB = (float*)smem;

    const int b = blockIdx.x & 7;            // XCD affinity (blockIdx%8 ~ XCD)
    const int p = blockIdx.x >> 3;           // 0..127 within batch
    const int mtg = (p & 1) ? (127 - (p >> 1)) : (p >> 1);  // pair light+heavy
    const int t0 = mtg * 16;

    const int tid = threadIdx.x;
    const int w = tid >> 6;          // wave 0..7
    const int lane = tid & 63;
    const int l15 = lane & 15;
    const int quad = lane >> 4;

    const int jd = mtg >> 2;         // diagonal-straddling KV tile
    const int ntt = jd + 1;
    const int js = (ntt * w) >> 3;
    const int je = (ntt * (w + 1)) >> 3;

    // Q fragments (A-layout): m = t0 + l15, k = h = quad*8 + j (+32)
    const bf16* qp = q + (size_t)(b * 2048 + t0 + l15) * 64 + quad * 8;
    bf16x8 qf0 = *(const bf16x8*)qp;
    bf16x8 qf1 = *(const bf16x8*)(qp + 32);

    floatx4 o[4] = {};
    float mi[4], li[4];
    #pragma unroll
    for (int r = 0; r < 4; r++) { mi[r] = -1e30f; li[r] = 0.f; }

    const int rowq = t0 + quad * 4;

    const bf16* kb0 = k + (size_t)(b * 2048 + l15) * 64 + quad * 8;    // + jt*4096 + nt*1024
    const bf16* vb0 = vT + (size_t)(b * 64 + l15) * 2048 + quad * 8;   // + nt*32768 + jt*64 + kc*32
    bf16* psw = psall + w * 16 * KP;

    for (int jt = js; jt < je; jt++) {
        // S = Q K^T : B[k=h][n=kv] direct from k[t][h] (L2-resident)
        const bf16* kp = kb0 + (size_t)jt * 4096;
        floatx4 s[4] = {};
        #pragma unroll
        for (int nt = 0; nt < 4; nt++) {
            bf16x8 k0 = *(const bf16x8*)(kp + nt * 1024);
            bf16x8 k1 = *(const bf16x8*)(kp + nt * 1024 + 32);
            s[nt] = MFMA16(qf0, k0, s[nt]);
            s[nt] = MFMA16(qf1, k1, s[nt]);
        }

        // causal mask (only the diagonal tile straddles)
        if (jt == jd) {
            #pragma unroll
            for (int nt = 0; nt < 4; nt++) {
                int kv = jt * 64 + nt * 16 + l15;
                #pragma unroll
                for (int r = 0; r < 4; r++)
                    if (kv > rowq + r) s[nt][r] = -1e30f;
            }
        }

        // online softmax per row r (row's 64 cols across the quad's 16 lanes)
        float alpha[4];
        #pragma unroll
        for (int r = 0; r < 4; r++) {
            float mx = fmaxf(fmaxf(s[0][r], s[1][r]), fmaxf(s[2][r], s[3][r]));
            #pragma unroll
            for (int off = 1; off < 16; off <<= 1) mx = fmaxf(mx, __shfl_xor(mx, off, 64));
            float mnew = fmaxf(mi[r], mx);
            float a = __expf(mi[r] - mnew);
            mi[r] = mnew;
            float rs = 0.f;
            #pragma unroll
            for (int nt = 0; nt < 4; nt++) {
                float pv = __expf(s[nt][r] - mnew);
                s[nt][r] = pv;
                rs += pv;
            }
            #pragma unroll
            for (int off = 1; off < 16; off <<= 1) rs += __shfl_xor(rs, off, 64);
            li[r] = li[r] * a + rs;
            alpha[r] = a;
        }
        #pragma unroll
        for (int nt = 0; nt < 4; nt++)
            #pragma unroll
            for (int r = 0; r < 4; r++)
                o[nt][r] *= alpha[r];

        // P: C-layout -> LDS -> A-layout (wave-private, no barrier)
        #pragma unroll
        for (int nt = 0; nt < 4; nt++)
            #pragma unroll
            for (int r = 0; r < 4; r++)
                psw[(quad * 4 + r) * KP + nt * 16 + l15] = (bf16)s[nt][r];

        // O += P V : B[k=kv][n=h] direct from vT[h][t]
        const bf16* vp = vb0 + jt * 64;
        #pragma unroll
        for (int kc = 0; kc < 2; kc++) {
            bf16x8 af = *(const bf16x8*)(psw + l15 * KP + kc * 32 + quad * 8);
            #pragma unroll
            for (int nt = 0; nt < 4; nt++) {
                bf16x8 vv = *(const bf16x8*)(vp + nt * 32768 + kc * 32);
                o[nt] = MFMA16(af, vv, o[nt]);
            }
        }
    }

    __syncthreads();   // everyone done with ps before Os overwrites it

    // dump partials (Os region unions with ps)
    #pragma unroll
    for (int r = 0; r < 4; r++) {
        if (l15 == 0) { Ms[w][quad * 4 + r] = mi[r]; Ls[w][quad * 4 + r] = li[r]; }
        #pragma unroll
        for (int nt = 0; nt < 4; nt++)
            OsB[(w * 16 + quad * 4 + r) * 68 + nt * 16 + l15] = o[nt][r];
    }
    __syncthreads();

    // merge 8 partials: thread -> (row = tid>>5, 2 cols = (tid&31)*2)
    {
        int row = tid >> 5;
        int c2 = (tid & 31) * 2;
        float Mg = -1e30f;
        #pragma unroll
        for (int u = 0; u < 8; u++) Mg = fmaxf(Mg, Ms[u][row]);
        float Lg = 0.f, v0 = 0.f, v1 = 0.f;
        #pragma unroll
        for (int u = 0; u < 8; u++) {
            float sw = __expf(Ms[u][row] - Mg);
            Lg += sw * Ls[u][row];
            const float* Or = OsB + (u * 16 + row) * 68 + c2;
            v0 += sw * Or[0];
            v1 += sw * Or[1];
        }
        float inv = 1.0f / Lg;
        float* op = out + (size_t)(b * 2048 + t0 + row) * 64 + c2;
        op[0] = v0 * inv;
        op[1] = v1 * inv;
    }
}

// ---------------------------------------------------------------------------
extern "C" void kernel_launch(void* const* d_in, const int* in_sizes, int n_in,
                              void* d_out, int out_size, void* d_ws, size_t ws_size,
                              hipStream_t stream) {
    const float* x  = (const float*)d_in[0];
    const float* Wq = (const float*)d_in[1];
    const float* Wk = (const float*)d_in[2];
    const float* Wv = (const float*)d_in[3];
    float* out = (float*)d_out;

    char* ws = (char*)d_ws;
    bf16* wTf = (bf16*)ws;                              // 393216 B + 1 KB slack
    bf16* q   = (bf16*)(ws + 394240);                   // 2 MB
    bf16* k   = (bf16*)(ws + 394240 + 2097152);
    bf16* vT  = (bf16*)(ws + 394240 + 2 * 2097152);     // [b*64+h][2048]

    hipLaunchKernelGGL(prep_w,   dim3(768),  dim3(256), 0, stream, Wq, Wk, Wv, wTf);
    hipLaunchKernelGGL(proj_qkv, dim3(512),  dim3(512), 0, stream, x, wTf, q, k, vT);
    hipLaunchKernelGGL(flash,    dim3(1024), dim3(512), 0, stream, q, k, vT, out);
}

// Round 5
// 144.233 us; speedup vs baseline: 1.8205x; 1.0944x over previous
//
#include <hip/hip_runtime.h>

typedef __bf16 bf16;
typedef __attribute__((ext_vector_type(8))) __bf16 bf16x8;
typedef __attribute__((ext_vector_type(4))) __bf16 bf16x4;
typedef __attribute__((ext_vector_type(4))) float floatx4;

#define MFMA16(a, b, c) __builtin_amdgcn_mfma_f32_16x16x32_bf16((a), (b), (c), 0, 0, 0)

// ---------------------------------------------------------------------------
// Kernel 0: W [1024][64] fp32 x3 -> wTf, FRAGMENT-MAJOR bf16:
//   wTf[(((mt*32 + kc)*4 + q)*16 + l)*8 + j] = A[m = mt*16+l][k = kc*32+q*8+j]
//   where A[m][c] = W_{m/64}[c][m%64].
// ---------------------------------------------------------------------------
__global__ void prep_w(const float* __restrict__ Wq, const float* __restrict__ Wk,
                       const float* __restrict__ Wv, bf16* __restrict__ wTf) {
    int tid = blockIdx.x * 256 + threadIdx.x;   // [0, 196608)
    int j = tid & 7;
    int l = (tid >> 3) & 15;
    int q = (tid >> 7) & 3;
    int kc = (tid >> 9) & 31;
    int mt = tid >> 14;                          // 0..11
    int mat = mt >> 2;
    int h = ((mt & 3) << 4) + l;
    int c = kc * 32 + q * 8 + j;
    const float* W = (mat == 0) ? Wq : (mat == 1) ? Wk : Wv;
    wTf[tid] = (bf16)W[c * 64 + h];
}

// ---------------------------------------------------------------------------
// Kernel 1: QKV projection. Block = 256 thr (4 waves) = ONE 16-row t-tile.
// Stage: 16 back-to-back float4 loads per thread (max loads-in-flight), then
//   convert+store bf16 to LDS (stride 1032 -> ~uniform bank phases).
// Compute: wave w = m-group w (3 m-tiles); A-frags stream from frag-major wTf
//   (L2) with DEPTH-2 register prefetch; B-frag = 1 ds_read_b128/iter.
// 33 KB LDS -> 4 blocks/CU: later blocks stage while earlier ones compute.
// ---------------------------------------------------------------------------
#define XSTR 1032

__global__ __launch_bounds__(256, 4) void proj_qkv(const float* __restrict__ x,
                                                   const bf16* __restrict__ wTf,
                                                   bf16* __restrict__ q,
                                                   bf16* __restrict__ k,
                                                   bf16* __restrict__ vT) {
    __shared__ bf16 xs[16 * XSTR];   // 33 KB

    const int tid = threadIdx.x;
    const int lane = tid & 63;
    const int w = tid >> 6;          // wave 0..3 = m-group
    const int l15 = lane & 15;
    const int quad = lane >> 4;
    const int T0 = blockIdx.x * 16;

    // ---- stage: thread (r = tid>>4, cm = tid&15): 16 loads first, then stores
    {
        const int r = tid >> 4;
        const int cm = tid & 15;
        const float* g = x + (size_t)(T0 + r) * 1024 + cm * 8;
        floatx4 f[16];
        #pragma unroll
        for (int c = 0; c < 8; c++) {
            f[2 * c]     = *(const floatx4*)(g + c * 128);
            f[2 * c + 1] = *(const floatx4*)(g + c * 128 + 4);
        }
        bf16* ld = xs + r * XSTR + cm * 8;
        #pragma unroll
        for (int c = 0; c < 8; c++) {
            bf16x8 pk;
            pk[0] = (bf16)f[2*c][0]; pk[1] = (bf16)f[2*c][1];
            pk[2] = (bf16)f[2*c][2]; pk[3] = (bf16)f[2*c][3];
            pk[4] = (bf16)f[2*c+1][0]; pk[5] = (bf16)f[2*c+1][1];
            pk[6] = (bf16)f[2*c+1][2]; pk[7] = (bf16)f[2*c+1][3];
            *(bf16x8*)(ld + c * 128) = pk;
        }
    }
    __syncthreads();

    // ---- compute: depth-2 A prefetch
    floatx4 acc[3] = {};
    const bf16* aw0 = wTf + (size_t)(w * 3 + 0) * 16384 + lane * 8;
    const bf16* aw1 = wTf + (size_t)(w * 3 + 1) * 16384 + lane * 8;
    const bf16* aw2 = wTf + (size_t)(w * 3 + 2) * 16384 + lane * 8;
    const bf16* xr = xs + l15 * XSTR + quad * 8;

    bf16x8 a0c = *(const bf16x8*)(aw0);
    bf16x8 a1c = *(const bf16x8*)(aw1);
    bf16x8 a2c = *(const bf16x8*)(aw2);
    bf16x8 a0n = *(const bf16x8*)(aw0 + 512);
    bf16x8 a1n = *(const bf16x8*)(aw1 + 512);
    bf16x8 a2n = *(const bf16x8*)(aw2 + 512);

    #pragma unroll 4
    for (int kc = 0; kc < 32; kc++) {
        // issue kc+2 loads early (2-iteration slack; reads 4KB slack past end)
        bf16x8 p0 = *(const bf16x8*)(aw0 + (kc + 2) * 512);
        bf16x8 p1 = *(const bf16x8*)(aw1 + (kc + 2) * 512);
        bf16x8 p2 = *(const bf16x8*)(aw2 + (kc + 2) * 512);
        bf16x8 bb = *(const bf16x8*)(xr + kc * 32);
        acc[0] = MFMA16(a0c, bb, acc[0]);
        acc[1] = MFMA16(a1c, bb, acc[1]);
        acc[2] = MFMA16(a2c, bb, acc[2]);
        a0c = a0n; a1c = a1n; a2c = a2n;
        a0n = p0;  a1n = p1;  a2n = p2;
    }

    // Epilogue. C-layout: (i,r) -> out-row m = (w*3+i)*16 + quad*4 + r
    // (mat = m/64, h = m%64), out-col t = T0 + l15. q gets 1/8 scale folded.
    const int t = T0 + l15;
    #pragma unroll
    for (int i = 0; i < 3; i++) {
        int mtile = w * 3 + i;
        int mat = mtile >> 2;                          // wave-uniform
        int hbase = ((mtile & 3) << 4) + (quad << 2);
        float sc = (mat == 0) ? 0.125f : 1.0f;
        bf16x4 pk;
        pk[0] = (bf16)(acc[i][0] * sc);
        pk[1] = (bf16)(acc[i][1] * sc);
        pk[2] = (bf16)(acc[i][2] * sc);
        pk[3] = (bf16)(acc[i][3] * sc);
        if (mat == 0) {
            *(bf16x4*)(q + (size_t)t * 64 + hbase) = pk;
        } else if (mat == 1) {
            *(bf16x4*)(k + (size_t)t * 64 + hbase) = pk;
        } else {
            int b = t >> 11, tt = t & 2047;
            #pragma unroll
            for (int r = 0; r < 4; r++)
                vT[(size_t)(b * 64 + hbase + r) * 2048 + tt] = pk[r];
        }
    }
}

// ---------------------------------------------------------------------------
// Kernel 2: causal flash attention, S^T formulation, uniform two-tile blocks.
// Block = 512 thr (8 waves) owns Q-tiles (p, 127-p): total KV work 32-34
// tiles for EVERY block (dispatch-mapping-proof balance). Waves split the
// flat KV-slot list 8 ways, each with private online-softmax state.
// S^T = K Q^T: each lane's 16 S values belong to ONE q-row (q = lane&15) ->
// softmax = local reg reduction + 2 shfls; m/l are per-lane scalars.
// PV: O^T = V^T P^T (A = vT contiguous, B = P^T via wave-private LDS).
// ---------------------------------------------------------------------------
#define KP2 72
#define OH 68

__global__ __launch_bounds__(512, 4) void flash(const bf16* __restrict__ q,
                                                const bf16* __restrict__ k,
                                                const bf16* __restrict__ vT,
                                                float* __restrict__ out) {
    __shared__ char smem[8 * 16 * OH * 4];   // union: ps (loop) / Os (merge)
    __shared__ float Ms[8][16], Ls[8][16];
    bf16* psall = (bf16*)smem;
    float* Os = (float*)smem;                // [w][q=16][OH]

    const int b = blockIdx.x & 7;            // batch -> XCD affinity
    const int p = blockIdx.x >> 3;           // 0..63
    const int t0A = p * 16;
    const int t0B = (127 - p) * 16;
    const int nttA = (p >> 2) + 1;
    const int nttB = ((127 - p) >> 2) + 1;
    const int L = nttA + nttB;               // 32..34 for all blocks

    const int tid = threadIdx.x;
    const int w = tid >> 6;
    const int lane = tid & 63;
    const int l15 = lane & 15;
    const int quad = lane >> 4;

    const int s0 = (L * w) >> 3;
    const int s1 = (L * (w + 1)) >> 3;

    const bf16* kbase = k + (size_t)(b * 2048 + l15) * 64 + quad * 8;   // + jt*4096 + mt*1024 + c*32
    const bf16* vbase = vT + (size_t)(b * 64 + l15) * 2048 + quad * 8;  // + mt*32768 + jt*64 + kc*32
    bf16* psw = psall + w * 16 * KP2;

    // Q B-frags: lane n=l15 -> q-row, k = h = quad*8+j (+32)
    const bf16* qpA = q + (size_t)(b * 2048 + t0A + l15) * 64 + quad * 8;
    const bf16* qpB = q + (size_t)(b * 2048 + t0B + l15) * 64 + quad * 8;

    floatx4 oA[4] = {}, oB[4] = {};
    float miA = -1e30f, liA = 0.f, miB = -1e30f, liB = 0.f;

#define KV_STEP(jtv, isdiag, t0v, qf0v, qf1v, mi_, li_, o_)                          \
    {                                                                                 \
        const bf16* kp = kbase + (size_t)(jtv) * 4096;                                \
        floatx4 stt[4];                                                               \
        _Pragma("unroll") for (int mt = 0; mt < 4; mt++) {                            \
            floatx4 z = {};                                                           \
            bf16x8 ka0 = *(const bf16x8*)(kp + mt * 1024);                            \
            bf16x8 ka1 = *(const bf16x8*)(kp + mt * 1024 + 32);                       \
            z = MFMA16(ka0, qf0v, z);                                                 \
            z = MFMA16(ka1, qf1v, z);                                                 \
            stt[mt] = z;                                                              \
        }                                                                             \
        if (isdiag) {                                                                 \
            _Pragma("unroll") for (int mt = 0; mt < 4; mt++)                          \
                _Pragma("unroll") for (int r = 0; r < 4; r++) {                       \
                    int kv = (jtv) * 64 + mt * 16 + quad * 4 + r;                     \
                    if (kv > (t0v) + l15) stt[mt][r] = -1e30f;                        \
                }                                                                     \
        }                                                                             \
        float mx = fmaxf(fmaxf(fmaxf(stt[0][0], stt[0][1]), fmaxf(stt[0][2], stt[0][3])),  \
                         fmaxf(fmaxf(stt[1][0], stt[1][1]), fmaxf(stt[1][2], stt[1][3]))); \
        mx = fmaxf(mx, fmaxf(fmaxf(fmaxf(stt[2][0], stt[2][1]), fmaxf(stt[2][2], stt[2][3])),  \
                             fmaxf(fmaxf(stt[3][0], stt[3][1]), fmaxf(stt[3][2], stt[3][3])))); \
        mx = fmaxf(mx, __shfl_xor(mx, 16, 64));                                       \
        mx = fmaxf(mx, __shfl_xor(mx, 32, 64));                                       \
        float mnew = fmaxf(mi_, mx);                                                  \
        float aa = __expf(mi_ - mnew);                                                \
        mi_ = mnew;                                                                   \
        float rs = 0.f;                                                               \
        _Pragma("unroll") for (int mt = 0; mt < 4; mt++)                              \
            _Pragma("unroll") for (int r = 0; r < 4; r++) {                           \
                float pv = __expf(stt[mt][r] - mnew);                                 \
                stt[mt][r] = pv;                                                      \
                rs += pv;                                                             \
            }                                                                         \
        rs += __shfl_xor(rs, 16, 64);                                                 \
        rs += __shfl_xor(rs, 32, 64);                                                 \
        li_ = li_ * aa + rs;                                                          \
        _Pragma("unroll") for (int mt = 0; mt < 4; mt++)                              \
            _Pragma("unroll") for (int r = 0; r < 4; r++) o_[mt][r] *= aa;            \
        _Pragma("unroll") for (int mt = 0; mt < 4; mt++) {                            \
            bf16x4 pk;                                                                \
            pk[0] = (bf16)stt[mt][0]; pk[1] = (bf16)stt[mt][1];                       \
            pk[2] = (bf16)stt[mt][2]; pk[3] = (bf16)stt[mt][3];                       \
            *(bf16x4*)(psw + l15 * KP2 + mt * 16 + quad * 4) = pk;                    \
        }                                                                             \
        const bf16* vp = vbase + (jtv) * 64;                                          \
        _Pragma("unroll") for (int kc = 0; kc < 2; kc++) {                            \
            bf16x8 pb = *(const bf16x8*)(psw + l15 * KP2 + kc * 32 + quad * 8);       \
            _Pragma("unroll") for (int mt = 0; mt < 4; mt++) {                        \
                bf16x8 va = *(const bf16x8*)(vp + mt * 32768 + kc * 32);              \
                o_[mt] = MFMA16(va, pb, o_[mt]);                                      \
            }                                                                         \
        }                                                                             \
    }

    // ---- tile A slots: s in [s0, min(s1, nttA)), jt = s
    {
        const int eA = (s1 < nttA) ? s1 : nttA;
        if (s0 < eA) {
            bf16x8 qf0 = *(const bf16x8*)qpA;
            bf16x8 qf1 = *(const bf16x8*)(qpA + 32);
            for (int s = s0; s < eA; s++) {
                KV_STEP(s, (s == nttA - 1), t0A, qf0, qf1, miA, liA, oA);
            }
        }
    }
    // ---- tile B slots: s in [max(s0, nttA), s1), jt = s - nttA
    {
        const int sB = (s0 > nttA) ? s0 : nttA;
        if (sB < s1) {
            bf16x8 qf0 = *(const bf16x8*)qpB;
            bf16x8 qf1 = *(const bf16x8*)(qpB + 32);
            for (int s = sB; s < s1; s++) {
                KV_STEP(s - nttA, (s == L - 1), t0B, qf0, qf1, miB, liB, oB);
            }
        }
    }

    // ---- merge tile A then tile B (Os region unions with ps)
    #pragma unroll
    for (int tile = 0; tile < 2; tile++) {
        __syncthreads();
        float mi = tile ? miB : miA;
        float li = tile ? liB : liA;
        if (lane < 16) { Ms[w][lane] = mi; Ls[w][lane] = li; }
        #pragma unroll
        for (int mt = 0; mt < 4; mt++) {
            floatx4 ov = tile ? oB[mt] : oA[mt];
            *(floatx4*)(Os + (w * 16 + l15) * OH + mt * 16 + quad * 4) = ov;
        }
        __syncthreads();
        {
            int qq = tid >> 5;               // 0..15
            int h2 = (tid & 31) * 2;         // 0..62
            float Mg = -1e30f;
            #pragma unroll
            for (int u = 0; u < 8; u++) Mg = fmaxf(Mg, Ms[u][qq]);
            float Lg = 0.f, v0 = 0.f, v1 = 0.f;
            #pragma unroll
            for (int u = 0; u < 8; u++) {
                float sw = __expf(Ms[u][qq] - Mg);
                Lg += sw * Ls[u][qq];
                const float* Or = Os + (u * 16 + qq) * OH + h2;
                v0 += sw * Or[0];
                v1 += sw * Or[1];
            }
            float inv = 1.0f / Lg;
            int t0v = tile ? t0B : t0A;
            float* op = out + (size_t)(b * 2048 + t0v + qq) * 64 + h2;
            op[0] = v0 * inv;
            op[1] = v1 * inv;
        }
    }
#undef KV_STEP
}

// ---------------------------------------------------------------------------
extern "C" void kernel_launch(void* const* d_in, const int* in_sizes, int n_in,
                              void* d_out, int out_size, void* d_ws, size_t ws_size,
                              hipStream_t stream) {
    const float* x  = (const float*)d_in[0];
    const float* Wq = (const float*)d_in[1];
    const float* Wk = (const float*)d_in[2];
    const float* Wv = (const float*)d_in[3];
    float* out = (float*)d_out;

    char* ws = (char*)d_ws;
    bf16* wTf = (bf16*)ws;                              // 393216 B + 4 KB slack
    bf16* q   = (bf16*)(ws + 397312);                   // 2 MB
    bf16* k   = (bf16*)(ws + 397312 + 2097152);
    bf16* vT  = (bf16*)(ws + 397312 + 2 * 2097152);     // [b*64+h][2048]

    hipLaunchKernelGGL(prep_w,   dim3(768),  dim3(256), 0, stream, Wq, Wk, Wv, wTf);
    hipLaunchKernelGGL(proj_qkv, dim3(1024), dim3(256), 0, stream, x, wTf, q, k, vT);
    hipLaunchKernelGGL(flash,    dim3(512),  dim3(512), 0, stream, q, k, vT, out);
}